// Round 8
// baseline (363.226 us; speedup 1.0000x reference)
//
#include <hip/hip_runtime.h>
#include <hip/hip_bf16.h>
#include <math.h>

#define DM 1024
#define DS 16
#define DI 2048
#define NB 2
#define LL 2048
#define BL (NB*LL)
#define LC 32
#define NC (LL/LC)   // 64

typedef __attribute__((ext_vector_type(8))) short short8;
typedef __attribute__((ext_vector_type(8))) unsigned short ushort8;
typedef __attribute__((ext_vector_type(4))) float f32x4;

__device__ __forceinline__ float silu_f(float x){ return x / (1.f + __expf(-x)); }
__device__ __forceinline__ float softplus_f(float x){ return (x > 15.f) ? x : log1pf(__expf(x)); }
__device__ __forceinline__ unsigned short f2bf(float f){
  unsigned u = __float_as_uint(f);
  u += 0x7fff + ((u >> 16) & 1);
  return (unsigned short)(u >> 16);
}
__device__ __forceinline__ float bf2f(unsigned short v){
  return __uint_as_float(((unsigned)v) << 16);
}

// ---------------- fp32 -> bf16 convert (single segment) ----------------
__global__ __launch_bounds__(256) void f2b_k(const float* __restrict__ src,
                                             unsigned short* __restrict__ dst, int n)
{
  int i = (blockIdx.x * 256 + threadIdx.x) * 8;
  if (i >= n) return;
  float4 v0 = *(const float4*)&src[i];
  float4 v1 = *(const float4*)&src[i + 4];
  ushort8 o;
  o[0]=f2bf(v0.x); o[1]=f2bf(v0.y); o[2]=f2bf(v0.z); o[3]=f2bf(v0.w);
  o[4]=f2bf(v1.x); o[5]=f2bf(v1.y); o[6]=f2bf(v1.z); o[7]=f2bf(v1.w);
  *(ushort8*)&dst[i] = o;
}

// ---------------- fp32 -> bf16 convert, 4 segments in one launch -------
__global__ __launch_bounds__(256) void f2b_multi(
    const float* __restrict__ s0, unsigned short* __restrict__ d0, int c0,
    const float* __restrict__ s1, unsigned short* __restrict__ d1, int c1,
    const float* __restrict__ s2, unsigned short* __restrict__ d2, int c2,
    const float* __restrict__ s3, unsigned short* __restrict__ d3, int c3)
{
  int b = blockIdx.x;
  const float* s; unsigned short* d;
  if (b < c0)              { s = s0; d = d0; }
  else if ((b -= c0) < c1) { s = s1; d = d1; }
  else if ((b -= c1) < c2) { s = s2; d = d2; }
  else                     { b -= c2; s = s3; d = d3; }
  int i = (b * 256 + threadIdx.x) * 8;
  float4 v0 = *(const float4*)&s[i];
  float4 v1 = *(const float4*)&s[i + 4];
  ushort8 o;
  o[0]=f2bf(v0.x); o[1]=f2bf(v0.y); o[2]=f2bf(v0.z); o[3]=f2bf(v0.w);
  o[4]=f2bf(v1.x); o[5]=f2bf(v1.y); o[6]=f2bf(v1.z); o[7]=f2bf(v1.w);
  *(ushort8*)&d[i] = o;
}

// ---------------- bf16 MFMA GEMM, reg-staged split-barrier pipeline ----
// C[M][N] = A[M][K] @ Bw[N][K]^T.  BM=128, BN=256, BK=64.
// 8 waves as 2(M) x 4(N); wave tile 64x64 (32 MFMA : 16 ds_read_b128).
// Schedule per K-tile t (buf q = t&1):
//   16 ds_read -> regs; lgkmcnt(0); s_barrier        [all waves done w/ buf q]
//   stage(t+2 -> buf q)                               [tile t lives in regs]
//   32 MFMA
//   vmcnt(6); s_barrier                               [t+1 landed; t+2 in flight]
// Raw s_barrier (no implicit vmcnt drain); vmcnt never 0 in steady state.
// XOR swizzle ch^=(row&7) on global source AND ds_read (0 bank conflicts).
template<int EPI, int OUTBF>
__global__ __launch_bounds__(512, 1) void gemm5(
    const unsigned short* __restrict__ A, const unsigned short* __restrict__ Bw,
    const float* __restrict__ bias, void* __restrict__ Cp,
    int N, int K)
{
  constexpr int BM = 128, BN = 256;
  __shared__ unsigned short lds[2][(BM + BN) * 64];
  const int t0 = threadIdx.x;
  const int wid = t0 >> 6, lane = t0 & 63;
  const int nbx = N / BN;
  const int cpx = (int)gridDim.x >> 3;
  const int bid = (int)blockIdx.x;
  const int swz = (bid & 7) * cpx + (bid >> 3);
  const int bm = (swz / nbx) * BM, bn = (swz % nbx) * BN;
  const int wm = (wid >> 2) * 64, wn = (wid & 3) * 64;

  f32x4 acc[4][4] = {};

  auto stage = [&](int buf, int kt) {
    const int k0 = kt * 64;
    #pragma unroll
    for (int s = 0; s < 6; s++) {
      int g = wid * 6 + s;                 // 0..47, wave-uniform
      int row = g * 8 + (lane >> 3);       // 0..383
      int ch  = (lane & 7) ^ (lane >> 3);  // source chunk, inverse-swizzled
      const unsigned short* src;
      if (g < 16) src = A  + (size_t)(bm + row) * K + k0 + ch * 8;
      else        src = Bw + (size_t)(bn + row - BM) * K + k0 + ch * 8;
      __builtin_amdgcn_global_load_lds(
          (const __attribute__((address_space(1))) void*)src,
          (__attribute__((address_space(3))) void*)(&lds[buf][(size_t)g * 512]), 16, 0, 0);
    }
  };

  stage(0, 0);
  stage(1, 1);
  asm volatile("s_waitcnt vmcnt(6)" ::: "memory");   // tile 0 landed
  __builtin_amdgcn_s_barrier();

  const int nk = K >> 6;

#define G5_READS(Q)                                                          \
  short8 af[2][4], bfr[2][4];                                                \
  _Pragma("unroll")                                                          \
  for (int ks = 0; ks < 2; ks++) {                                           \
    int cc = ((ks << 2) + (lane >> 4)) ^ (lane & 7);                         \
    _Pragma("unroll")                                                        \
    for (int i = 0; i < 4; i++) {                                            \
      af[ks][i]  = *(const short8*)&lds[Q][(wm + i * 16 + (lane & 15)) * 64 + cc * 8]; \
      bfr[ks][i] = *(const short8*)&lds[Q][BM * 64 + (wn + i * 16 + (lane & 15)) * 64 + cc * 8]; \
    }                                                                        \
  }

#define G5_MFMA()                                                            \
  _Pragma("unroll")                                                          \
  for (int ks = 0; ks < 2; ks++)                                             \
    _Pragma("unroll")                                                        \
    for (int i = 0; i < 4; i++)                                              \
      _Pragma("unroll")                                                      \
      for (int j = 0; j < 4; j++)                                            \
        acc[i][j] = __builtin_amdgcn_mfma_f32_16x16x32_bf16(af[ks][i], bfr[ks][j], acc[i][j], 0, 0, 0);

  for (int t = 0; t < nk - 2; t++) {
    const int q = t & 1;
    G5_READS(q)
    asm volatile("s_waitcnt lgkmcnt(0)" ::: "memory");
    __builtin_amdgcn_sched_barrier(0);
    __builtin_amdgcn_s_barrier();            // all waves done reading buf q
    stage(q, t + 2);                         // overwrite buf q (tile t is in regs)
    __builtin_amdgcn_sched_barrier(0);
    G5_MFMA()
    __builtin_amdgcn_sched_barrier(0);
    asm volatile("s_waitcnt vmcnt(6)" ::: "memory");   // tile t+1 landed
    __builtin_amdgcn_s_barrier();
  }
  {                                          // t = nk-2: no stage
    const int q = (nk - 2) & 1;
    G5_READS(q)
    G5_MFMA()
    __builtin_amdgcn_sched_barrier(0);
    asm volatile("s_waitcnt vmcnt(0)" ::: "memory");   // tile nk-1 landed
    __builtin_amdgcn_s_barrier();
  }
  {                                          // t = nk-1
    const int q = (nk - 1) & 1;
    G5_READS(q)
    G5_MFMA()
  }
#undef G5_READS
#undef G5_MFMA

  #pragma unroll
  for (int i = 0; i < 4; i++) {
    #pragma unroll
    for (int j = 0; j < 4; j++) {
      int col = bn + wn + j * 16 + (lane & 15);
      float bv = (EPI == 1) ? bias[col] : 0.f;
      #pragma unroll
      for (int r = 0; r < 4; r++) {
        int row = bm + wm + i * 16 + (lane >> 4) * 4 + r;
        float v = acc[i][j][r];
        if (EPI == 1) v = softplus_f(v + bv);
        if (OUTBF) ((unsigned short*)Cp)[(size_t)row * N + col] = f2bf(v);
        else       ((float*)Cp)[(size_t)row * N + col] = v;
      }
    }
  }
}

// ---------------- causal depthwise conv (k=4) + bias + SiLU -> bf16 ----
__global__ __launch_bounds__(256) void conv_silu_k(
    const unsigned short* __restrict__ xz, const float* __restrict__ cw,
    const float* __restrict__ cb, unsigned short* __restrict__ xa)
{
  int v = blockIdx.x * 256 + threadIdx.x;   // over BL*DI/8
  int d8 = (v & (DI/8 - 1)) * 8;
  int bl = v >> 8;
  int l  = bl & (LL - 1);
  float acc[8];
  #pragma unroll
  for (int j = 0; j < 8; j++) acc[j] = cb[d8 + j];
  size_t rowb = (size_t)bl * (2 * DI) + d8;
  #pragma unroll
  for (int k = 0; k < 4; k++) {
    int ls = l - 3 + k;
    if (ls >= 0) {
      ushort8 xv = *(const ushort8*)&xz[rowb + (size_t)(k - 3) * (2 * DI)];
      #pragma unroll
      for (int j = 0; j < 8; j++) acc[j] += bf2f(xv[j]) * cw[(d8 + j) * 4 + k];
    }
  }
  ushort8 o;
  #pragma unroll
  for (int j = 0; j < 8; j++) o[j] = f2bf(silu_f(acc[j]));
  *(ushort8*)&xa[(size_t)bl * DI + d8] = o;
}

// ---------------- bc = xa @ x_proj_w^T  (N=32) -------------------------
__global__ __launch_bounds__(256) void bc_k(
    const unsigned short* __restrict__ xa, const unsigned short* __restrict__ w,
    float* __restrict__ bc)
{
  __shared__ unsigned short sx[8 * DI];
  const int t = threadIdx.x;
  const size_t base = (size_t)blockIdx.x * 8 * DI;
  #pragma unroll
  for (int it = 0; it < 8; it++) {
    int v = t + it * 256;
    *(ushort8*)&sx[v * 8] = *(const ushort8*)&xa[base + (size_t)v * 8];
  }
  __syncthreads();
  const int m = t >> 5, n = t & 31;
  const unsigned short* wr = w + (size_t)n * DI;
  const unsigned short* xr = sx + m * DI;
  float acc = 0.f;
  #pragma unroll 4
  for (int k = 0; k < DI; k += 8) {
    ushort8 xv = *(const ushort8*)&xr[k];
    ushort8 wv = *(const ushort8*)&wr[k];
    #pragma unroll
    for (int j = 0; j < 8; j++) acc += bf2f(xv[j]) * bf2f(wv[j]);
  }
  bc[(size_t)(blockIdx.x * 8 + m) * 32 + n] = acc;
}

// ---------------- chunked selective scan -------------------------------
__global__ __launch_bounds__(256) void scan_part1(
    const float* __restrict__ dlt, const unsigned short* __restrict__ xa,
    const float* __restrict__ bc, const float* __restrict__ A_log,
    float* __restrict__ S_arr, float* __restrict__ sumdlt)
{
  const int bid = blockIdx.x;           // NB*NC*8 = 1024
  const int b = bid >> 9;
  const int c = (bid >> 3) & (NC - 1);
  const int dg = bid & 7;
  const int t = threadIdx.x;
  const int d = dg * 256 + t;
  float Ac[16];
  #pragma unroll
  for (int n = 0; n < 16; n++) Ac[n] = -__expf(A_log[d * 16 + n]);
  __shared__ float sB[LC][16];
  for (int e = t; e < LC * 16; e += 256) {
    int l = e >> 4, n = e & 15;
    sB[l][n] = bc[(size_t)(b * LL + c * LC + l) * 32 + n];
  }
  __syncthreads();
  float h[16] = {};
  float sd = 0.f;
  size_t rowbase = (size_t)(b * LL + c * LC) * DI + d;
  for (int l = 0; l < LC; l++) {
    float dl = dlt[rowbase + (size_t)l * DI];
    float u  = bf2f(xa[rowbase + (size_t)l * DI]);
    float w = dl * u;
    sd += dl;
    #pragma unroll
    for (int n = 0; n < 16; n++) {
      float dA = __expf(dl * Ac[n]);
      h[n] = dA * h[n] + w * sB[l][n];
    }
  }
  float* Sp = S_arr + ((size_t)(b * NC + c) * DI + d) * 16;
  #pragma unroll
  for (int n = 0; n < 16; n++) Sp[n] = h[n];
  sumdlt[(size_t)(b * NC + c) * DI + d] = sd;
}

__global__ __launch_bounds__(256) void scan_combine(
    const float* __restrict__ A_log, const float* __restrict__ sumdlt,
    float* __restrict__ S_arr)
{
  int tid = blockIdx.x * 256 + threadIdx.x;   // NB*DI*16 = 65536
  int n = tid & 15;
  int d = (tid >> 4) & (DI - 1);
  int b = tid >> 15;
  float Ac = -__expf(A_log[d * 16 + n]);
  float h = 0.f;
  for (int c = 0; c < NC; c++) {
    size_t idx = ((size_t)(b * NC + c) * DI + d) * 16 + n;
    float S = S_arr[idx];
    float P = __expf(sumdlt[(size_t)(b * NC + c) * DI + d] * Ac);
    S_arr[idx] = h;
    h = P * h + S;
  }
}

__global__ __launch_bounds__(256) void scan_part2(
    const float* __restrict__ dlt, const unsigned short* __restrict__ xa,
    const float* __restrict__ bc, const float* __restrict__ A_log,
    const float* __restrict__ Dp, const unsigned short* __restrict__ xz,
    const float* __restrict__ Hin, unsigned short* __restrict__ y)
{
  const int bid = blockIdx.x;
  const int b = bid >> 9;
  const int c = (bid >> 3) & (NC - 1);
  const int dg = bid & 7;
  const int t = threadIdx.x;
  const int d = dg * 256 + t;
  float Ac[16];
  #pragma unroll
  for (int n = 0; n < 16; n++) Ac[n] = -__expf(A_log[d * 16 + n]);
  __shared__ float sB[LC][16];
  __shared__ float sC[LC][16];
  for (int e = t; e < LC * 16; e += 256) {
    int l = e >> 4, n = e & 15;
    size_t row = (size_t)(b * LL + c * LC + l) * 32;
    sB[l][n] = bc[row + n];
    sC[l][n] = bc[row + 16 + n];
  }
  __syncthreads();
  float h[16];
  const float* Hp = Hin + ((size_t)(b * NC + c) * DI + d) * 16;
  #pragma unroll
  for (int n = 0; n < 16; n++) h[n] = Hp[n];
  const float Dv = Dp[d];
  size_t rowbase = (size_t)(b * LL + c * LC) * DI + d;
  for (int l = 0; l < LC; l++) {
    float dl = dlt[rowbase + (size_t)l * DI];
    float u  = bf2f(xa[rowbase + (size_t)l * DI]);
    float w = dl * u;
    float ya = 0.f;
    #pragma unroll
    for (int n = 0; n < 16; n++) {
      float dA = __expf(dl * Ac[n]);
      h[n] = dA * h[n] + w * sB[l][n];
      ya += h[n] * sC[l][n];
    }
    float zz = bf2f(xz[(size_t)(b * LL + c * LC + l) * (2 * DI) + DI + d]);
    y[rowbase + (size_t)l * DI] = f2bf((ya + u * Dv) * silu_f(zz));
  }
}

extern "C" void kernel_launch(void* const* d_in, const int* in_sizes, int n_in,
                              void* d_out, int out_size, void* d_ws, size_t ws_size,
                              hipStream_t stream)
{
  const float* x    = (const float*)d_in[0];
  const float* Win  = (const float*)d_in[1];
  const float* cw   = (const float*)d_in[2];
  const float* cb   = (const float*)d_in[3];
  const float* Wxp  = (const float*)d_in[4];
  const float* Wdt  = (const float*)d_in[5];
  const float* bdt  = (const float*)d_in[6];
  const float* Alog = (const float*)d_in[7];
  const float* Dp   = (const float*)d_in[8];
  const float* Wout = (const float*)d_in[9];
  float* out = (float*)d_out;

  float* ws = (float*)d_ws;
  float* dlt    = ws;                        //  8,388,608 f
  float* bcb    = dlt + 8388608;             //    131,072 f
  float* S_arr  = bcb + 131072;              //  4,194,304 f
  float* sumdlt = S_arr + 4194304;           //    262,144 f
  unsigned short* xz_bf = (unsigned short*)(sumdlt + 262144); // 16,777,216 us
  unsigned short* xa_bf = xz_bf + 16777216;  //  8,388,608 us
  unsigned short* y_bf  = xa_bf + 8388608;   //  8,388,608 us
  unsigned short* x_bf  = y_bf;              // 4,194,304 us (dead before y written)
  unsigned short* win_bf= y_bf + 4194304;    // 4,194,304 us (dead before y written)
  unsigned short* wbuf  = y_bf + 8388608;    //  4,194,304 us (Wdt, then Wout)
  unsigned short* wxp_bf= wbuf + 4194304;    //     65,536 us

  // 0) upfront conversions: x, Win, Wdt, Wxp (counts in 2048-elem blocks)
  f2b_multi<<<dim3(2048 + 2048 + 2048 + 32), dim3(256), 0, stream>>>(
      x, x_bf, 2048, Win, win_bf, 2048, Wdt, wbuf, 2048, Wxp, wxp_bf, 32);
  // 1) xz = x @ in_proj_w^T   [4096 x 4096], K=1024 -> bf16
  gemm5<0,1><<<dim3(512), dim3(512), 0, stream>>>(x_bf, win_bf, nullptr, xz_bf, 2*DI, DM);
  // 2) x_act = silu(causal_conv(x_ssm)) -> bf16
  conv_silu_k<<<dim3(BL*DI/8/256), dim3(256), 0, stream>>>(xz_bf, cw, cb, xa_bf);
  // 3) delta = softplus(x_act @ dt_proj_w^T + b)   [4096 x 2048], K=2048 -> fp32
  gemm5<1,0><<<dim3(256), dim3(512), 0, stream>>>(xa_bf, wbuf, bdt, dlt, DI, DI);
  // convert Wout into wbuf (stream-ordered after dt GEMM consumed Wdt)
  f2b_k<<<dim3(DM*DI/2048), dim3(256), 0, stream>>>(Wout, wbuf, DM*DI);
  // 4) bc = x_act @ x_proj_w^T   [4096 x 32]
  bc_k<<<dim3(BL/8), dim3(256), 0, stream>>>(xa_bf, wxp_bf, bcb);
  // 5) chunked selective scan
  scan_part1<<<dim3(NB*NC*8), dim3(256), 0, stream>>>(dlt, xa_bf, bcb, Alog, S_arr, sumdlt);
  scan_combine<<<dim3(NB*DI*DS/256), dim3(256), 0, stream>>>(Alog, sumdlt, S_arr);
  scan_part2<<<dim3(NB*NC*8), dim3(256), 0, stream>>>(dlt, xa_bf, bcb, Alog, Dp, xz_bf, S_arr, y_bf);
  // 6) out = y @ out_proj_w^T   [4096 x 1024], K=2048 -> fp32  (N=DM!)
  gemm5<0,0><<<dim3(128), dim3(512), 0, stream>>>(y_bf, wbuf, nullptr, out, DM, DI);
}

// Round 9
// 341.065 us; speedup vs baseline: 1.0650x; 1.0650x over previous
//
#include <hip/hip_runtime.h>
#include <hip/hip_bf16.h>
#include <math.h>

#define DM 1024
#define DS 16
#define DI 2048
#define NB 2
#define LL 2048
#define BL (NB*LL)
#define LC 32
#define NC (LL/LC)   // 64

typedef __attribute__((ext_vector_type(8))) short short8;
typedef __attribute__((ext_vector_type(8))) unsigned short ushort8;
typedef __attribute__((ext_vector_type(4))) float f32x4;

__device__ __forceinline__ float silu_f(float x){ return x / (1.f + __expf(-x)); }
__device__ __forceinline__ float softplus_f(float x){ return (x > 15.f) ? x : log1pf(__expf(x)); }
__device__ __forceinline__ unsigned short f2bf(float f){
  unsigned u = __float_as_uint(f);
  u += 0x7fff + ((u >> 16) & 1);
  return (unsigned short)(u >> 16);
}
__device__ __forceinline__ float bf2f(unsigned short v){
  return __uint_as_float(((unsigned)v) << 16);
}

// ---------------- fp32 -> bf16 convert (single segment) ----------------
__global__ __launch_bounds__(256) void f2b_k(const float* __restrict__ src,
                                             unsigned short* __restrict__ dst, int n)
{
  int i = (blockIdx.x * 256 + threadIdx.x) * 8;
  if (i >= n) return;
  float4 v0 = *(const float4*)&src[i];
  float4 v1 = *(const float4*)&src[i + 4];
  ushort8 o;
  o[0]=f2bf(v0.x); o[1]=f2bf(v0.y); o[2]=f2bf(v0.z); o[3]=f2bf(v0.w);
  o[4]=f2bf(v1.x); o[5]=f2bf(v1.y); o[6]=f2bf(v1.z); o[7]=f2bf(v1.w);
  *(ushort8*)&dst[i] = o;
}

// ---------------- fp32 -> bf16 convert, 4 segments in one launch -------
__global__ __launch_bounds__(256) void f2b_multi(
    const float* __restrict__ s0, unsigned short* __restrict__ d0, int c0,
    const float* __restrict__ s1, unsigned short* __restrict__ d1, int c1,
    const float* __restrict__ s2, unsigned short* __restrict__ d2, int c2,
    const float* __restrict__ s3, unsigned short* __restrict__ d3, int c3)
{
  int b = blockIdx.x;
  const float* s; unsigned short* d;
  if (b < c0)              { s = s0; d = d0; }
  else if ((b -= c0) < c1) { s = s1; d = d1; }
  else if ((b -= c1) < c2) { s = s2; d = d2; }
  else                     { b -= c2; s = s3; d = d3; }
  int i = (b * 256 + threadIdx.x) * 8;
  float4 v0 = *(const float4*)&s[i];
  float4 v1 = *(const float4*)&s[i + 4];
  ushort8 o;
  o[0]=f2bf(v0.x); o[1]=f2bf(v0.y); o[2]=f2bf(v0.z); o[3]=f2bf(v0.w);
  o[4]=f2bf(v1.x); o[5]=f2bf(v1.y); o[6]=f2bf(v1.z); o[7]=f2bf(v1.w);
  *(ushort8*)&d[i] = o;
}

// ---------------- bf16 MFMA GEMM, 4-phase interleaved pipeline ---------
// C[M][N] = A[M][K] @ Bw[N][K]^T.  BM=128, BN in {256,128}, BK=64.
// 8 waves 2(M) x 4(N); wave tile 64 x BN/4.  Per K-tile: 4 MFMA clusters
// (ks,jh); each phase issues NEXT cluster's ds_reads, then MFMAs current
// cluster (LDS pipe overlaps MFMA pipe).  Tile boundary (P3):
//   BAR1 (all waves' buf-q reads drained) -> stage(q, t+2) -> vmcnt(SL)
//   -> BAR2 (ALL waves' t+1 loads landed; vmcnt is per-wave, barrier
//   makes it collective) -> read next tile's first cluster from q^1.
// vmcnt never 0 in steady state.  XOR swizzle ch^=(row&7) both sides.
template<int BN, int EPI, int OUTBF>
__global__ __launch_bounds__(512, 1) void gemm6(
    const unsigned short* __restrict__ A, const unsigned short* __restrict__ Bw,
    const float* __restrict__ bias, void* __restrict__ Cp,
    int N, int K)
{
  constexpr int BM = 128;
  constexpr int WN = BN / 4;
  constexpr int NRJ = WN / 16;            // 4 or 2
  constexpr int NH = NRJ / 2;             // frags per bf cluster: 2 or 1
  constexpr int SL = (BM + BN) / 64;      // gloads per thread per stage: 6 or 4
  __shared__ unsigned short lds[2][(BM + BN) * 64];
  const int t0i = threadIdx.x;
  const int wid = t0i >> 6, lane = t0i & 63;
  const int nbx = N / BN;
  const int cpx = (int)gridDim.x >> 3;
  const int bid = (int)blockIdx.x;
  const int swz = (bid & 7) * cpx + (bid >> 3);
  const int bm = (swz / nbx) * BM, bn = (swz % nbx) * BN;
  const int wm = (wid >> 2) * 64, wn = (wid & 3) * WN;
  const int ln15 = lane & 15, l16 = lane >> 4, lx7 = lane & 7;

  f32x4 acc[4][NRJ] = {};
  short8 af[2][4];
  short8 bfr[2][NH];

  auto stage = [&](int buf, int kt) {
    const int k0 = kt * 64;
    #pragma unroll
    for (int s = 0; s < SL; s++) {
      int g = wid * SL + s;                // wave-uniform
      int row = g * 8 + (lane >> 3);
      int ch  = lx7 ^ (lane >> 3);         // inverse-swizzled source chunk
      const unsigned short* src;
      if (g < 16) src = A  + (size_t)(bm + row) * K + k0 + ch * 8;
      else        src = Bw + (size_t)(bn + row - BM) * K + k0 + ch * 8;
      __builtin_amdgcn_global_load_lds(
          (const __attribute__((address_space(1))) void*)src,
          (__attribute__((address_space(3))) void*)(&lds[buf][(size_t)g * 512]), 16, 0, 0);
    }
  };
  auto read_af = [&](short8* dst, const unsigned short* buf, int ks) {
    int cc = ((ks << 2) + l16) ^ lx7;
    #pragma unroll
    for (int i = 0; i < 4; i++)
      dst[i] = *(const short8*)&buf[(wm + i * 16 + ln15) * 64 + cc * 8];
  };
  auto read_bf = [&](short8* dst, const unsigned short* buf, int ks, int jh) {
    int cc = ((ks << 2) + l16) ^ lx7;
    #pragma unroll
    for (int j = 0; j < NH; j++)
      dst[j] = *(const short8*)&buf[BM * 64 + (wn + (jh * NH + j) * 16 + ln15) * 64 + cc * 8];
  };
  auto cluster = [&](short8* a, short8* b, int jh) {
    #pragma unroll
    for (int i = 0; i < 4; i++)
      #pragma unroll
      for (int j = 0; j < NH; j++)
        acc[i][jh * NH + j] = __builtin_amdgcn_mfma_f32_16x16x32_bf16(a[i], b[j], acc[i][jh * NH + j], 0, 0, 0);
  };

#define SB    __builtin_amdgcn_sched_barrier(0)
#define LGKM0 asm volatile("s_waitcnt lgkmcnt(0)" ::: "memory")
#define PRIO1 __builtin_amdgcn_s_setprio(1)
#define PRIO0 __builtin_amdgcn_s_setprio(0)

  // macro: one K-tile.  Entry: af[0],bfr[0] hold cluster-0 frags of tile T.
#define G6_TILE(T, Q, STG, VMN)                                              \
  { const unsigned short* bq  = &lds[Q][0];                                  \
    const unsigned short* bq1 = &lds[(Q) ^ 1][0];                            \
    /* P0 */                                                                 \
    read_bf(bfr[1], bq, 0, 1); SB;                                           \
    PRIO1; cluster(af[0], bfr[0], 0); PRIO0; LGKM0; SB;                      \
    /* P1 */                                                                 \
    read_af(af[1], bq, 1); read_bf(bfr[0], bq, 1, 0); SB;                    \
    PRIO1; cluster(af[0], bfr[1], 1); PRIO0; LGKM0; SB;                      \
    /* P2 */                                                                 \
    read_bf(bfr[1], bq, 1, 1); SB;                                           \
    PRIO1; cluster(af[1], bfr[0], 0); PRIO0; LGKM0; SB;                      \
    /* P3 */                                                                 \
    __builtin_amdgcn_s_barrier();                                            \
    if (STG) stage(Q, (T) + 2);                                              \
    asm volatile("s_waitcnt vmcnt(%0)" :: "n"(VMN) : "memory"); SB;          \
    __builtin_amdgcn_s_barrier();                                            \
    read_af(af[0], bq1, 0); read_bf(bfr[0], bq1, 0, 0); SB;                  \
    PRIO1; cluster(af[1], bfr[1], 1); PRIO0; LGKM0; SB; }

  const int nk = K >> 6;                   // 16 or 32 (even, >= 4)

  // prologue
  stage(0, 0); stage(1, 1);
  asm volatile("s_waitcnt vmcnt(%0)" :: "n"(SL) : "memory");
  __builtin_amdgcn_s_barrier();            // all waves' tile-0 loads landed
  read_af(af[0], &lds[0][0], 0); read_bf(bfr[0], &lds[0][0], 0, 0);
  LGKM0; SB;

  // main: tiles 0 .. nk-3 (pairs -> static buffer parity)
  for (int tp = 0; tp < (nk - 2) / 2; ++tp) {
    const int tv = tp * 2;
    G6_TILE(tv, 0, true, SL)
    G6_TILE(tv + 1, 1, true, SL)
  }
  // tile nk-2 (q=0): no stage; drain all (only nk-1's loads outstanding)
  G6_TILE(nk - 2, 0, false, 0)
  // tile nk-1 (q=1): minimal
  {
    const unsigned short* b1 = &lds[1][0];
    read_bf(bfr[1], b1, 0, 1); SB;
    PRIO1; cluster(af[0], bfr[0], 0); PRIO0; LGKM0; SB;
    read_af(af[1], b1, 1); read_bf(bfr[0], b1, 1, 0); SB;
    PRIO1; cluster(af[0], bfr[1], 1); PRIO0; LGKM0; SB;
    read_bf(bfr[1], b1, 1, 1); SB;
    PRIO1; cluster(af[1], bfr[0], 0); PRIO0; LGKM0; SB;
    PRIO1; cluster(af[1], bfr[1], 1); PRIO0;
  }
#undef G6_TILE
#undef SB
#undef LGKM0
#undef PRIO1
#undef PRIO0

  #pragma unroll
  for (int i = 0; i < 4; i++) {
    #pragma unroll
    for (int j = 0; j < NRJ; j++) {
      int col = bn + wn + j * 16 + ln15;
      float bv = (EPI == 1) ? bias[col] : 0.f;
      #pragma unroll
      for (int r = 0; r < 4; r++) {
        int row = bm + wm + i * 16 + l16 * 4 + r;
        float v = acc[i][j][r];
        if (EPI == 1) v = softplus_f(v + bv);
        if (OUTBF) ((unsigned short*)Cp)[(size_t)row * N + col] = f2bf(v);
        else       ((float*)Cp)[(size_t)row * N + col] = v;
      }
    }
  }
}

// ---------------- causal depthwise conv (k=4) + bias + SiLU -> bf16 ----
__global__ __launch_bounds__(256) void conv_silu_k(
    const unsigned short* __restrict__ xz, const float* __restrict__ cw,
    const float* __restrict__ cb, unsigned short* __restrict__ xa)
{
  int v = blockIdx.x * 256 + threadIdx.x;   // over BL*DI/8
  int d8 = (v & (DI/8 - 1)) * 8;
  int bl = v >> 8;
  int l  = bl & (LL - 1);
  float acc[8];
  #pragma unroll
  for (int j = 0; j < 8; j++) acc[j] = cb[d8 + j];
  size_t rowb = (size_t)bl * (2 * DI) + d8;
  #pragma unroll
  for (int k = 0; k < 4; k++) {
    int ls = l - 3 + k;
    if (ls >= 0) {
      ushort8 xv = *(const ushort8*)&xz[rowb + (size_t)(k - 3) * (2 * DI)];
      #pragma unroll
      for (int j = 0; j < 8; j++) acc[j] += bf2f(xv[j]) * cw[(d8 + j) * 4 + k];
    }
  }
  ushort8 o;
  #pragma unroll
  for (int j = 0; j < 8; j++) o[j] = f2bf(silu_f(acc[j]));
  *(ushort8*)&xa[(size_t)bl * DI + d8] = o;
}

// ---------------- bc = xa @ x_proj_w^T  (N=32) -------------------------
__global__ __launch_bounds__(256) void bc_k(
    const unsigned short* __restrict__ xa, const unsigned short* __restrict__ w,
    float* __restrict__ bc)
{
  __shared__ unsigned short sx[8 * DI];
  const int t = threadIdx.x;
  const size_t base = (size_t)blockIdx.x * 8 * DI;
  #pragma unroll
  for (int it = 0; it < 8; it++) {
    int v = t + it * 256;
    *(ushort8*)&sx[v * 8] = *(const ushort8*)&xa[base + (size_t)v * 8];
  }
  __syncthreads();
  const int m = t >> 5, n = t & 31;
  const unsigned short* wr = w + (size_t)n * DI;
  const unsigned short* xr = sx + m * DI;
  float acc = 0.f;
  #pragma unroll 4
  for (int k = 0; k < DI; k += 8) {
    ushort8 xv = *(const ushort8*)&xr[k];
    ushort8 wv = *(const ushort8*)&wr[k];
    #pragma unroll
    for (int j = 0; j < 8; j++) acc += bf2f(xv[j]) * bf2f(wv[j]);
  }
  bc[(size_t)(blockIdx.x * 8 + m) * 32 + n] = acc;
}

// ---------------- chunked selective scan -------------------------------
__global__ __launch_bounds__(256) void scan_part1(
    const float* __restrict__ dlt, const unsigned short* __restrict__ xa,
    const float* __restrict__ bc, const float* __restrict__ A_log,
    float* __restrict__ S_arr, float* __restrict__ sumdlt)
{
  const int bid = blockIdx.x;           // NB*NC*8 = 1024
  const int b = bid >> 9;
  const int c = (bid >> 3) & (NC - 1);
  const int dg = bid & 7;
  const int t = threadIdx.x;
  const int d = dg * 256 + t;
  float Ac[16];
  #pragma unroll
  for (int n = 0; n < 16; n++) Ac[n] = -__expf(A_log[d * 16 + n]);
  __shared__ float sB[LC][16];
  for (int e = t; e < LC * 16; e += 256) {
    int l = e >> 4, n = e & 15;
    sB[l][n] = bc[(size_t)(b * LL + c * LC + l) * 32 + n];
  }
  __syncthreads();
  float h[16] = {};
  float sd = 0.f;
  size_t rowbase = (size_t)(b * LL + c * LC) * DI + d;
  for (int l = 0; l < LC; l++) {
    float dl = dlt[rowbase + (size_t)l * DI];
    float u  = bf2f(xa[rowbase + (size_t)l * DI]);
    float w = dl * u;
    sd += dl;
    #pragma unroll
    for (int n = 0; n < 16; n++) {
      float dA = __expf(dl * Ac[n]);
      h[n] = dA * h[n] + w * sB[l][n];
    }
  }
  float* Sp = S_arr + ((size_t)(b * NC + c) * DI + d) * 16;
  #pragma unroll
  for (int n = 0; n < 16; n++) Sp[n] = h[n];
  sumdlt[(size_t)(b * NC + c) * DI + d] = sd;
}

__global__ __launch_bounds__(256) void scan_combine(
    const float* __restrict__ A_log, const float* __restrict__ sumdlt,
    float* __restrict__ S_arr)
{
  int tid = blockIdx.x * 256 + threadIdx.x;   // NB*DI*16 = 65536
  int n = tid & 15;
  int d = (tid >> 4) & (DI - 1);
  int b = tid >> 15;
  float Ac = -__expf(A_log[d * 16 + n]);
  float h = 0.f;
  for (int c = 0; c < NC; c++) {
    size_t idx = ((size_t)(b * NC + c) * DI + d) * 16 + n;
    float S = S_arr[idx];
    float P = __expf(sumdlt[(size_t)(b * NC + c) * DI + d] * Ac);
    S_arr[idx] = h;
    h = P * h + S;
  }
}

__global__ __launch_bounds__(256) void scan_part2(
    const float* __restrict__ dlt, const unsigned short* __restrict__ xa,
    const float* __restrict__ bc, const float* __restrict__ A_log,
    const float* __restrict__ Dp, const unsigned short* __restrict__ xz,
    const float* __restrict__ Hin, unsigned short* __restrict__ y)
{
  const int bid = blockIdx.x;
  const int b = bid >> 9;
  const int c = (bid >> 3) & (NC - 1);
  const int dg = bid & 7;
  const int t = threadIdx.x;
  const int d = dg * 256 + t;
  float Ac[16];
  #pragma unroll
  for (int n = 0; n < 16; n++) Ac[n] = -__expf(A_log[d * 16 + n]);
  __shared__ float sB[LC][16];
  __shared__ float sC[LC][16];
  for (int e = t; e < LC * 16; e += 256) {
    int l = e >> 4, n = e & 15;
    size_t row = (size_t)(b * LL + c * LC + l) * 32;
    sB[l][n] = bc[row + n];
    sC[l][n] = bc[row + 16 + n];
  }
  __syncthreads();
  float h[16];
  const float* Hp = Hin + ((size_t)(b * NC + c) * DI + d) * 16;
  #pragma unroll
  for (int n = 0; n < 16; n++) h[n] = Hp[n];
  const float Dv = Dp[d];
  size_t rowbase = (size_t)(b * LL + c * LC) * DI + d;
  for (int l = 0; l < LC; l++) {
    float dl = dlt[rowbase + (size_t)l * DI];
    float u  = bf2f(xa[rowbase + (size_t)l * DI]);
    float w = dl * u;
    float ya = 0.f;
    #pragma unroll
    for (int n = 0; n < 16; n++) {
      float dA = __expf(dl * Ac[n]);
      h[n] = dA * h[n] + w * sB[l][n];
      ya += h[n] * sC[l][n];
    }
    float zz = bf2f(xz[(size_t)(b * LL + c * LC + l) * (2 * DI) + DI + d]);
    y[rowbase + (size_t)l * DI] = f2bf((ya + u * Dv) * silu_f(zz));
  }
}

extern "C" void kernel_launch(void* const* d_in, const int* in_sizes, int n_in,
                              void* d_out, int out_size, void* d_ws, size_t ws_size,
                              hipStream_t stream)
{
  const float* x    = (const float*)d_in[0];
  const float* Win  = (const float*)d_in[1];
  const float* cw   = (const float*)d_in[2];
  const float* cb   = (const float*)d_in[3];
  const float* Wxp  = (const float*)d_in[4];
  const float* Wdt  = (const float*)d_in[5];
  const float* bdt  = (const float*)d_in[6];
  const float* Alog = (const float*)d_in[7];
  const float* Dp   = (const float*)d_in[8];
  const float* Wout = (const float*)d_in[9];
  float* out = (float*)d_out;

  float* ws = (float*)d_ws;
  float* dlt    = ws;                        //  8,388,608 f
  float* bcb    = dlt + 8388608;             //    131,072 f
  float* S_arr  = bcb + 131072;              //  4,194,304 f
  float* sumdlt = S_arr + 4194304;           //    262,144 f
  unsigned short* xz_bf = (unsigned short*)(sumdlt + 262144); // 16,777,216 us
  unsigned short* xa_bf = xz_bf + 16777216;  //  8,388,608 us
  unsigned short* y_bf  = xa_bf + 8388608;   //  8,388,608 us
  unsigned short* x_bf  = y_bf;              // 4,194,304 us (dead before y written)
  unsigned short* win_bf= y_bf + 4194304;    // 4,194,304 us (dead before y written)
  unsigned short* wbuf  = y_bf + 8388608;    //  4,194,304 us (Wdt, then Wout)
  unsigned short* wxp_bf= wbuf + 4194304;    //     65,536 us

  // 0) upfront conversions: x, Win, Wdt, Wxp (counts in 2048-elem blocks)
  f2b_multi<<<dim3(2048 + 2048 + 2048 + 32), dim3(256), 0, stream>>>(
      x, x_bf, 2048, Win, win_bf, 2048, Wdt, wbuf, 2048, Wxp, wxp_bf, 32);
  // 1) xz = x @ in_proj_w^T   [4096 x 4096], K=1024 -> bf16
  gemm6<256,0,1><<<dim3(512), dim3(512), 0, stream>>>(x_bf, win_bf, nullptr, xz_bf, 2*DI, DM);
  // 2) x_act = silu(causal_conv(x_ssm)) -> bf16
  conv_silu_k<<<dim3(BL*DI/8/256), dim3(256), 0, stream>>>(xz_bf, cw, cb, xa_bf);
  // 3) delta = softplus(x_act @ dt_proj_w^T + b)   [4096 x 2048], K=2048 -> fp32
  gemm6<256,1,0><<<dim3(256), dim3(512), 0, stream>>>(xa_bf, wbuf, bdt, dlt, DI, DI);
  // convert Wout into wbuf (stream-ordered after dt GEMM consumed Wdt)
  f2b_k<<<dim3(DM*DI/2048), dim3(256), 0, stream>>>(Wout, wbuf, DM*DI);
  // 4) bc = x_act @ x_proj_w^T   [4096 x 32]
  bc_k<<<dim3(BL/8), dim3(256), 0, stream>>>(xa_bf, wxp_bf, bcb);
  // 5) chunked selective scan
  scan_part1<<<dim3(NB*NC*8), dim3(256), 0, stream>>>(dlt, xa_bf, bcb, Alog, S_arr, sumdlt);
  scan_combine<<<dim3(NB*DI*DS/256), dim3(256), 0, stream>>>(Alog, sumdlt, S_arr);
  scan_part2<<<dim3(NB*NC*8), dim3(256), 0, stream>>>(dlt, xa_bf, bcb, Alog, Dp, xz_bf, S_arr, y_bf);
  // 6) out = y @ out_proj_w^T   [4096 x 1024], K=2048 -> fp32  (BN=128, grid 256)
  gemm6<128,0,0><<<dim3(256), dim3(512), 0, stream>>>(y_bf, wbuf, nullptr, out, DM, DI);
}